// Round 2
// baseline (299.033 us; speedup 1.0000x reference)
//
#include <hip/hip_runtime.h>

typedef unsigned short u16;

#define N_SP   3136     // 56*56
#define BNCOL  25088    // B * N_SP
#define NDIM   384
#define NINNER 512
#define SCALE_F 0.125f

typedef __attribute__((ext_vector_type(8))) short bf16x8;
typedef __attribute__((ext_vector_type(4))) float f32x4;

#define AS1 __attribute__((address_space(1)))
#define AS3 __attribute__((address_space(3)))

__device__ __forceinline__ float bf2f(u16 u) {
  union { unsigned int i; float f; } v; v.i = ((unsigned int)u) << 16; return v.f;
}
__device__ __forceinline__ u16 f2bf(float f) {
  union { float f; unsigned int i; } v; v.f = f;
  unsigned int r = v.i + 0x7fffu + ((v.i >> 16) & 1u);   // RNE
  return (u16)(r >> 16);
}

// async global->LDS, 16B per lane. lds base must be wave-uniform; lane i lands at lds + i*16B.
__device__ __forceinline__ void g2l16(const u16* g, u16* l) {
  __builtin_amdgcn_global_load_lds((const AS1 unsigned int*)g,
                                   (AS3 unsigned int*)l, 16, 0, 0);
}

// ---------- weight fp32 -> bf16 convert + BN-folded depthwise weights ----------
__global__ __launch_bounds__(256) void cvt_kernel(
    const float* __restrict__ a, const float* __restrict__ b, const float* __restrict__ c,
    u16* __restrict__ oa, u16* __restrict__ ob, u16* __restrict__ oc,
    const float* __restrict__ qdw, const float* __restrict__ qg, const float* __restrict__ qb2,
    const float* __restrict__ qm,  const float* __restrict__ qv,
    const float* __restrict__ kdw, const float* __restrict__ kg, const float* __restrict__ kb2,
    const float* __restrict__ km,  const float* __restrict__ kvv,
    float* __restrict__ fused)
{
  int i = blockIdx.x * 256 + threadIdx.x;
  if (i < 196608) oa[i] = f2bf(a[i]);
  ob[i] = f2bf(b[i]);               // grid sized exactly to 393216
  if (i < 196608) oc[i] = f2bf(c[i]);
  if (i < NDIM) {
    float invq = qg[i] * rsqrtf(qv[i] + 1e-5f);
    float invk = kg[i] * rsqrtf(kvv[i] + 1e-5f);
    float* f = fused + i * 20;
#pragma unroll
    for (int j = 0; j < 9; ++j) { f[j] = qdw[i*9+j] * invq; f[10+j] = kdw[i*9+j] * invk; }
    f[9]  = qb2[i] - qm[i] * invq;
    f[19] = kb2[i] - km[i] * invk;
  }
}

// ---------- fused depthwise 3x3 conv + BN (q and kv paths), output (BN, C) bf16 ----------
__global__ __launch_bounds__(256) void dwbn_kernel(
    const float* __restrict__ x, const float* __restrict__ fused,
    u16* __restrict__ yq, u16* __restrict__ ykv)
{
  __shared__ u16 Lq[64][40];
  __shared__ u16 Lk[64][40];
  int tid = threadIdx.x;
  int bb = blockIdx.z, c0 = blockIdx.y * 32, p0 = blockIdx.x * 64;
  int pl = tid & 63;
  int cg = __builtin_amdgcn_readfirstlane(tid >> 6);   // wave-uniform channel group
  int p = p0 + pl;
  int h = p / 56, w = p - h * 56;
  int roff[3], coff[3];
  float mr[3], mc[3];
#pragma unroll
  for (int d = 0; d < 3; ++d) {
    int r = h + d - 1;
    bool vr = (r >= 0) && (r < 56);
    roff[d] = (vr ? r : h) * 56;
    mr[d] = vr ? 1.f : 0.f;
    int cc = w + d - 1;
    bool vc = (cc >= 0) && (cc < 56);
    coff[d] = vc ? cc : w;
    mc[d] = vc ? 1.f : 0.f;
  }
  float m9[9];
#pragma unroll
  for (int dh = 0; dh < 3; ++dh)
#pragma unroll
    for (int dw = 0; dw < 3; ++dw) m9[dh*3+dw] = mr[dh] * mc[dw];

  __attribute__((aligned(16))) u16 oq[8], ok[8];
#pragma unroll
  for (int i = 0; i < 8; ++i) {
    int c = c0 + cg * 8 + i;
    const float* xp = x + ((size_t)bb * NDIM + c) * N_SP;
    const float* f = fused + c * 20;
    float v[9];
#pragma unroll
    for (int dh = 0; dh < 3; ++dh)
#pragma unroll
      for (int dw = 0; dw < 3; ++dw)
        v[dh*3+dw] = xp[roff[dh] + coff[dw]];
    float sq = f[9], sk = f[19];
#pragma unroll
    for (int j = 0; j < 9; ++j) {
      float xm = v[j] * m9[j];
      sq += xm * f[j];
      sk += xm * f[10+j];
    }
    oq[i] = f2bf(sq); ok[i] = f2bf(sk);
  }
  *(ushort4*)&Lq[pl][cg * 8]     = *(ushort4*)&oq[0];
  *(ushort4*)&Lq[pl][cg * 8 + 4] = *(ushort4*)&oq[4];
  *(ushort4*)&Lk[pl][cg * 8]     = *(ushort4*)&ok[0];
  *(ushort4*)&Lk[pl][cg * 8 + 4] = *(ushort4*)&ok[4];
  __syncthreads();
  int pr = tid >> 2, cc2 = (tid & 3) * 8;
  size_t g = ((size_t)bb * N_SP + p0 + pr) * NDIM + c0 + cc2;
  *(ushort4*)(yq + g)      = *(ushort4*)&Lq[pr][cc2];
  *(ushort4*)(yq + g + 4)  = *(ushort4*)&Lq[pr][cc2 + 4];
  *(ushort4*)(ykv + g)     = *(ushort4*)&Lk[pr][cc2];
  *(ushort4*)(ykv + g + 4) = *(ushort4*)&Lk[pr][cc2 + 4];
}

// ---------- MFMA GEMM: D[m][n] = sum_k A[m][k] * B[n][k]  (NT form) ----------
// mode 0: LDS-transpose, store bf16 rows of n: Cout[n][m] (stride Cstride).
// mode 1: +bias, fp32 NCHW scatter (m = channel, n = bn).
// Swizzle: Nt==8 (KV, shared tile is A): bid&7 == mt&7 -> all 8 nt-siblings of an
//          A-tile on ONE XCD (L2-resident). Else (shared tile is B): old scheme,
//          mt-siblings of one nt already share bid&7.
struct GemmLds {
  union {
    struct { u16 A[128 * 32]; u16 B[128 * 32]; } s;   // [row][k] 8KB each
    u16 T[64 * 132];                                   // epilogue transpose chunk (16.9KB)
  } u;
};

__device__ __forceinline__ void gemm_body(GemmLds& lds, int bid,
    const u16* __restrict__ A, const u16* __restrict__ B, int Kd,
    u16* __restrict__ Cout, int Cstride,
    int mode, const float* __restrict__ bias, float* __restrict__ Out, int Mt, int Nt)
{
  int mt, nt;
  if (Nt == 8) {
    int low = bid & 7;                 // XCD slot == mt & 7
    nt = (bid >> 3) & 7;
    mt = (bid >> 6) * 8 + low;
    if (mt >= Mt) return;
  } else {
    int r = bid & 7, g = bid >> 3;
    mt = g % Mt; nt = (g / Mt) * 8 + r;
    if (nt >= Nt) return;
  }
  int m0 = mt * 128, n0 = nt * 128;

  int tid = threadIdx.x;
  int lane = tid & 63, wv = tid >> 6;
  int wm = (wv >> 1) * 64, wn = (wv & 1) * 64;
  int srow = lane >> 2;          // 0..15
  int sch = (lane & 3) * 8;      // k chunk
  int arow0 = wv * 32;           // each wave stages 32 rows of A and B
  const u16* Ag = A + (size_t)(m0 + arow0 + srow) * Kd + sch;
  const u16* Bg = B + (size_t)(n0 + arow0 + srow) * Kd + sch;
  u16* Al = &lds.u.s.A[arow0 * 32];
  u16* Bl = &lds.u.s.B[arow0 * 32];
  f32x4 acc[4][4];
#pragma unroll
  for (int i = 0; i < 4; ++i)
#pragma unroll
    for (int j = 0; j < 4; ++j) acc[i][j] = (f32x4){0.f, 0.f, 0.f, 0.f};

  int ml = lane & 15, q8 = (lane >> 4) * 8;
  for (int k0 = 0; k0 < Kd; k0 += 32) {
    g2l16(Ag + k0, Al);
    g2l16(Ag + k0 + (size_t)16 * Kd, Al + 16 * 32);
    g2l16(Bg + k0, Bl);
    g2l16(Bg + k0 + (size_t)16 * Kd, Bl + 16 * 32);
    __syncthreads();
    bf16x8 af[4], bfr[4];
#pragma unroll
    for (int i = 0; i < 4; ++i) {
      af[i]  = *(const bf16x8*)&lds.u.s.A[(wm + i * 16 + ml) * 32 + q8];
      bfr[i] = *(const bf16x8*)&lds.u.s.B[(wn + i * 16 + ml) * 32 + q8];
    }
#pragma unroll
    for (int i = 0; i < 4; ++i)
#pragma unroll
      for (int j = 0; j < 4; ++j)
        acc[i][j] = __builtin_amdgcn_mfma_f32_16x16x32_bf16(af[i], bfr[j], acc[i][j], 0, 0, 0);
    __syncthreads();
  }

  if (mode == 0) {
    int q4 = (lane >> 4) * 4;
#pragma unroll
    for (int ph = 0; ph < 2; ++ph) {
      if (ph) __syncthreads();         // previous chunk's readers done
      if ((wv & 1) == ph) {            // waves whose wn == ph*64
#pragma unroll
        for (int i = 0; i < 4; ++i)
#pragma unroll
          for (int j = 0; j < 4; ++j) {
            int nl = j * 16 + ml;      // 0..63 local n
            int m = wm + i * 16 + q4;
            ushort4 o;
            o.x = f2bf(acc[i][j][0]); o.y = f2bf(acc[i][j][1]);
            o.z = f2bf(acc[i][j][2]); o.w = f2bf(acc[i][j][3]);
            *(ushort4*)&lds.u.T[nl * 132 + m] = o;
          }
      }
      __syncthreads();
#pragma unroll
      for (int it = 0; it < 4; ++it) {
        int nl = it * 16 + (tid >> 4);
        int mc = (tid & 15) * 8;
        ushort4 a = *(ushort4*)&lds.u.T[nl * 132 + mc];
        ushort4 b = *(ushort4*)&lds.u.T[nl * 132 + mc + 4];
        u16* gp = Cout + (size_t)(n0 + ph * 64 + nl) * Cstride + m0 + mc;
        *(ushort4*)gp = a;
        *(ushort4*)(gp + 4) = b;
      }
    }
  } else {
    int q4 = (lane >> 4) * 4;
#pragma unroll
    for (int i = 0; i < 4; ++i)
#pragma unroll
      for (int j = 0; j < 4; ++j) {
        int n = n0 + wn + j * 16 + ml;
        int bb = n / N_SP, p = n - bb * N_SP;
#pragma unroll
        for (int rr = 0; rr < 4; ++rr) {
          int m = m0 + wm + i * 16 + q4 + rr;
          Out[((size_t)bb * NDIM + m) * N_SP + p] = acc[i][j][rr] + bias[m];
        }
      }
  }
}

__global__ __launch_bounds__(256) void mfma_gemm(
    const u16* __restrict__ A, const u16* __restrict__ B, int Kd,
    u16* __restrict__ Cout, int Cstride,
    int mode, const float* __restrict__ bias, float* __restrict__ Out, int Mt, int Nt)
{
  __shared__ GemmLds lds;
  gemm_body(lds, blockIdx.x, A, B, Kd, Cout, Cstride, mode, bias, Out, Mt, Nt);
}

// Q GEMM (800 blocks) + KV GEMM (1600 blocks) in ONE launch: tail of Q fills with
// head of KV. Offset 800 is 0 mod 8 so KV's bid&7 <-> XCD association is preserved.
__global__ __launch_bounds__(256) void mfma_gemm_qkv(
    const u16* __restrict__ Wq, const u16* __restrict__ yq, u16* __restrict__ Qb,
    const u16* __restrict__ ykv, const u16* __restrict__ Wkv, u16* __restrict__ KVb)
{
  __shared__ GemmLds lds;
  int bid = blockIdx.x;
  if (bid < 800)
    gemm_body(lds, bid, Wq, yq, NDIM, Qb, NINNER, 0, nullptr, nullptr, 4, 196);
  else
    gemm_body(lds, bid - 800, ykv, Wkv, NDIM, KVb, BNCOL, 0, nullptr, nullptr, 196, 8);
}

// ---------- merged: ktv (448 blocks, longer -> dispatched first) + diag (784 blocks) ----------
// ktv[bh][d][e] = sum_p K[d][p] V[e][p]   (MFMA frags direct from global, 7-way atomic accum)
// diag[h][bn]   = SCALE * sum_d Q[bn][d] K[d][bn] ; m0 = sum   (dg now (h,bn): coalesced)
__global__ __launch_bounds__(256) void diag_ktv_kernel(
    const u16* __restrict__ Q, const u16* __restrict__ KV,
    float* __restrict__ dg, float* __restrict__ m0, float* __restrict__ ktv)
{
  __shared__ float wsum[4];
  int bid = blockIdx.x, tid = threadIdx.x;
  if (bid < 448) {
    // ---- ktv: bh = bid/7 owns cols [xb*448, xb*448+448) of batch bb ----
    int bh = bid / 7, xb = bid - bh * 7;
    int bb = bh >> 3, hh = bh & 7;
    int w = tid >> 6, lane = tid & 63;
    int ml = lane & 15, quad = lane >> 4, q8 = quad * 8;
    size_t colbase = (size_t)bb * N_SP + xb * 448 + q8;
    const u16* Ar = KV + (size_t)(hh * 64 + w * 16 + ml) * BNCOL + colbase;
    const u16* Br = KV + (size_t)(NINNER + hh * 64 + ml) * BNCOL + colbase;
    f32x4 acc[4];
#pragma unroll
    for (int j = 0; j < 4; ++j) acc[j] = (f32x4){0.f, 0.f, 0.f, 0.f};
#pragma unroll
    for (int t = 0; t < 14; ++t) {
      int po = t * 32;
      bf16x8 a = *(const bf16x8*)(Ar + po);
#pragma unroll
      for (int j = 0; j < 4; ++j) {
        bf16x8 b = *(const bf16x8*)(Br + (size_t)j * 16 * BNCOL + po);
        acc[j] = __builtin_amdgcn_mfma_f32_16x16x32_bf16(a, b, acc[j], 0, 0, 0);
      }
    }
    float* kt = ktv + bh * 4096;
#pragma unroll
    for (int j = 0; j < 4; ++j)
#pragma unroll
      for (int r = 0; r < 4; ++r)
        atomicAdd(&kt[(w * 16 + quad * 4 + r) * 64 + j * 16 + ml], acc[j][r]);
  } else {
    // ---- diag ----
    int b2 = bid - 448;
    int hh = b2 / 98, xb = b2 - hh * 98;
    int bn = xb * 256 + tid;
    const u16* qrow = Q + (size_t)bn * NINNER + hh * 64;
    const u16* kcol = KV + (size_t)(hh * 64) * BNCOL + bn;
    float s = 0.f;
#pragma unroll
    for (int d0 = 0; d0 < 64; d0 += 8) {
      ushort4 a = *(const ushort4*)(qrow + d0);
      ushort4 b = *(const ushort4*)(qrow + d0 + 4);
      const u16* kp = kcol + (size_t)d0 * BNCOL;
      s += bf2f(a.x) * bf2f(kp[0]);
      s += bf2f(a.y) * bf2f(kp[(size_t)1 * BNCOL]);
      s += bf2f(a.z) * bf2f(kp[(size_t)2 * BNCOL]);
      s += bf2f(a.w) * bf2f(kp[(size_t)3 * BNCOL]);
      s += bf2f(b.x) * bf2f(kp[(size_t)4 * BNCOL]);
      s += bf2f(b.y) * bf2f(kp[(size_t)5 * BNCOL]);
      s += bf2f(b.z) * bf2f(kp[(size_t)6 * BNCOL]);
      s += bf2f(b.w) * bf2f(kp[(size_t)7 * BNCOL]);
    }
    s *= SCALE_F;
    dg[(size_t)hh * BNCOL + bn] = s;     // (h, bn): coalesced
    float r = s;
#pragma unroll
    for (int off = 32; off > 0; off >>= 1) r += __shfl_down(r, off);
    if ((tid & 63) == 0) wsum[tid >> 6] = r;
    __syncthreads();
    if (tid == 0) atomicAdd(m0, wsum[0] + wsum[1] + wsum[2] + wsum[3]);
  }
}

// ---------- out[p][e] = (m0 - diag[p])*V[e][p] + SCALE * sum_d Q[p][d]*ktv[d][e] ----------
// MFMA: A = Q rows (global), B = ktv^T bf16 (LDS). Output (bn, c) via LDS transpose.
__global__ __launch_bounds__(256) void attn_out_kernel(
    const u16* __restrict__ Q, const u16* __restrict__ KV,
    const float* __restrict__ dg, const float* __restrict__ ktv,
    const float* __restrict__ m0p, u16* __restrict__ OutA)
{
  __shared__ u16 Bt[64][72];    // ktv^T [e][d] bf16
  __shared__ u16 T2[64][72];    // out transpose [p][e]
  __shared__ float ds2[64];
  int bh = blockIdx.y, bb = bh >> 3, hh = bh & 7;
  int p0 = blockIdx.x * 64;
  int tid = threadIdx.x;
  const float* kt = ktv + bh * 4096;
  for (int l = tid; l < 4096; l += 256) {
    int d = l >> 6, e = l & 63;
    Bt[e][d] = f2bf(kt[l]);
  }
  if (tid < 64) ds2[tid] = dg[(size_t)hh * BNCOL + bb * N_SP + p0 + tid];
  __syncthreads();
  int w = tid >> 6, lane = tid & 63;
  int ml = lane & 15, quad = lane >> 4, q8 = quad * 8;
  const u16* Ar = Q + ((size_t)bb * N_SP + p0 + w * 16 + ml) * NINNER + hh * 64 + q8;
  bf16x8 a0 = *(const bf16x8*)Ar;
  bf16x8 a1 = *(const bf16x8*)(Ar + 32);
  f32x4 acc[4];
#pragma unroll
  for (int j = 0; j < 4; ++j) acc[j] = (f32x4){0.f, 0.f, 0.f, 0.f};
#pragma unroll
  for (int j = 0; j < 4; ++j) {
    bf16x8 b0 = *(const bf16x8*)&Bt[j * 16 + ml][q8];
    bf16x8 b1 = *(const bf16x8*)&Bt[j * 16 + ml][32 + q8];
    acc[j] = __builtin_amdgcn_mfma_f32_16x16x32_bf16(a0, b0, acc[j], 0, 0, 0);
    acc[j] = __builtin_amdgcn_mfma_f32_16x16x32_bf16(a1, b1, acc[j], 0, 0, 0);
  }
  float m0v = *m0p;
  size_t pcol = (size_t)bb * N_SP + p0 + w * 16 + quad * 4;
#pragma unroll
  for (int j = 0; j < 4; ++j) {
    const u16* vr = KV + (size_t)(NINNER + hh * 64 + j * 16 + ml) * BNCOL + pcol;
    ushort4 vv = *(const ushort4*)vr;
    const u16* vp = (const u16*)&vv;
#pragma unroll
    for (int r = 0; r < 4; ++r) {
      float dvm = m0v - ds2[w * 16 + quad * 4 + r];
      float o = SCALE_F * acc[j][r] + dvm * bf2f(vp[r]);
      T2[w * 16 + quad * 4 + r][j * 16 + ml] = f2bf(o);
    }
  }
  __syncthreads();
  int pl = tid >> 2, ec = (tid & 3) * 16;
  u16* gp = OutA + ((size_t)bb * N_SP + p0 + pl) * NINNER + hh * 64 + ec;
  *(ushort4*)gp        = *(ushort4*)&T2[pl][ec];
  *(ushort4*)(gp + 4)  = *(ushort4*)&T2[pl][ec + 4];
  *(ushort4*)(gp + 8)  = *(ushort4*)&T2[pl][ec + 8];
  *(ushort4*)(gp + 12) = *(ushort4*)&T2[pl][ec + 12];
}

extern "C" void kernel_launch(void* const* d_in, const int* in_sizes, int n_in,
                              void* d_out, int out_size, void* d_ws, size_t ws_size,
                              hipStream_t stream)
{
  (void)in_sizes; (void)n_in; (void)out_size; (void)ws_size;
  const float* x      = (const float*)d_in[0];
  const float* wq_dw  = (const float*)d_in[1];
  const float* wq_g   = (const float*)d_in[2];
  const float* wq_b   = (const float*)d_in[3];
  const float* wq_m   = (const float*)d_in[4];
  const float* wq_v   = (const float*)d_in[5];
  const float* wq_pw  = (const float*)d_in[6];
  const float* wkv_dw = (const float*)d_in[7];
  const float* wkv_g  = (const float*)d_in[8];
  const float* wkv_b  = (const float*)d_in[9];
  const float* wkv_m  = (const float*)d_in[10];
  const float* wkv_v  = (const float*)d_in[11];
  const float* wkv_pw = (const float*)d_in[12];
  const float* wo     = (const float*)d_in[13];
  const float* bo     = (const float*)d_in[14];
  float* out = (float*)d_out;

  char* ws = (char*)d_ws;
  size_t off = 0;
  auto alloc = [&](size_t bytes) {
    void* p = ws + off; off = (off + bytes + 255) & ~(size_t)255; return p;
  };
  u16* yq   = (u16*)alloc((size_t)BNCOL * NDIM * 2);        // 19.27 MB  (BN, 384)
  u16* ykv  = (u16*)alloc((size_t)BNCOL * NDIM * 2);        // 19.27 MB  (BN, 384)
  u16* Qb   = (u16*)alloc((size_t)BNCOL * NINNER * 2);      // 25.69 MB  (BN, 512)
  u16* KVb  = (u16*)alloc((size_t)2 * NINNER * BNCOL * 2);  // 51.38 MB  (1024, BN): K rows 0..511, V rows 512..1023
  float* dgb  = (float*)alloc((size_t)BNCOL * 8 * 4);       // 0.80 MB   (h, bn)
  float* ktvb = (float*)alloc((size_t)64 * 4096 * 4 + 64);  // 1.05 MB (+m0 tail)
  u16* Wq  = (u16*)alloc((size_t)NINNER * NDIM * 2);        // 0.39 MB
  u16* Wkv = (u16*)alloc((size_t)2 * NINNER * NDIM * 2);    // 0.79 MB
  u16* Wo  = (u16*)alloc((size_t)NDIM * NINNER * 2);        // 0.39 MB
  float* fused = (float*)alloc((size_t)NDIM * 20 * 4);      // 30.7 KB BN-folded dw weights
  float* m0 = ktvb + 64 * 4096;
  u16* OutA = yq;   // alias: yq/ykv dead after the pw GEMMs; 25.7 MB fits in their 38.5 MB

  hipMemsetAsync(ktvb, 0, (size_t)64 * 4096 * 4 + 4, stream);

  cvt_kernel<<<1536, 256, 0, stream>>>(wq_pw, wkv_pw, wo, Wq, Wkv, Wo,
                                       wq_dw, wq_g, wq_b, wq_m, wq_v,
                                       wkv_dw, wkv_g, wkv_b, wkv_m, wkv_v, fused);

  dwbn_kernel<<<dim3(49, 12, 8), 256, 0, stream>>>(x, fused, yq, ykv);

  // Q (A=Wq, B=yq -> Qb) + KV swapped (A=ykv, B=Wkv -> KVb) in one launch
  mfma_gemm_qkv<<<dim3(800 + 1600), 256, 0, stream>>>(Wq, yq, Qb, ykv, Wkv, KVb);

  // ktv (448 blocks) + diag (784 blocks) in one launch
  diag_ktv_kernel<<<dim3(448 + 784), 256, 0, stream>>>(Qb, KVb, dgb, m0, ktvb);

  attn_out_kernel<<<dim3(49, 64), 256, 0, stream>>>(Qb, KVb, dgb, ktvb, m0, OutA);

  mfma_gemm<<<dim3(3 * 200), 256, 0, stream>>>(Wo, OutA, NINNER, nullptr, 0, 1, bo, out, 3, 196);
}

// Round 8
// 277.437 us; speedup vs baseline: 1.0778x; 1.0778x over previous
//
#include <hip/hip_runtime.h>

typedef unsigned short u16;

#define N_SP   3136     // 56*56
#define BNCOL  25088    // B * N_SP
#define NDIM   384
#define NINNER 512
#define SCALE_F 0.125f

typedef __attribute__((ext_vector_type(8))) short bf16x8;
typedef __attribute__((ext_vector_type(4))) float f32x4;

#define AS1 __attribute__((address_space(1)))
#define AS3 __attribute__((address_space(3)))

__device__ __forceinline__ float bf2f(u16 u) {
  union { unsigned int i; float f; } v; v.i = ((unsigned int)u) << 16; return v.f;
}
__device__ __forceinline__ u16 f2bf(float f) {
  union { float f; unsigned int i; } v; v.f = f;
  unsigned int r = v.i + 0x7fffu + ((v.i >> 16) & 1u);   // RNE
  return (u16)(r >> 16);
}

// async global->LDS, 16B per lane. lds base must be wave-uniform; lane i lands at lds + i*16B.
__device__ __forceinline__ void g2l16(const u16* g, u16* l) {
  __builtin_amdgcn_global_load_lds((const AS1 unsigned int*)g,
                                   (AS3 unsigned int*)l, 16, 0, 0);
}

// ---------- weight fp32 -> bf16 convert + BN-folded depthwise weights ----------
__global__ __launch_bounds__(256) void cvt_kernel(
    const float* __restrict__ a, const float* __restrict__ b, const float* __restrict__ c,
    u16* __restrict__ oa, u16* __restrict__ ob, u16* __restrict__ oc,
    const float* __restrict__ qdw, const float* __restrict__ qg, const float* __restrict__ qb2,
    const float* __restrict__ qm,  const float* __restrict__ qv,
    const float* __restrict__ kdw, const float* __restrict__ kg, const float* __restrict__ kb2,
    const float* __restrict__ km,  const float* __restrict__ kvv,
    float* __restrict__ fused)
{
  int i = blockIdx.x * 256 + threadIdx.x;
  if (i < 196608) oa[i] = f2bf(a[i]);
  ob[i] = f2bf(b[i]);               // grid sized exactly to 393216
  if (i < 196608) oc[i] = f2bf(c[i]);
  if (i < NDIM) {
    float invq = qg[i] * rsqrtf(qv[i] + 1e-5f);
    float invk = kg[i] * rsqrtf(kvv[i] + 1e-5f);
    float* f = fused + i * 20;
#pragma unroll
    for (int j = 0; j < 9; ++j) { f[j] = qdw[i*9+j] * invq; f[10+j] = kdw[i*9+j] * invk; }
    f[9]  = qb2[i] - qm[i] * invq;
    f[19] = kb2[i] - km[i] * invk;
  }
}

// ---------- fused depthwise 3x3 conv + BN (q and kv paths), output (BN, C) bf16 ----------
__global__ __launch_bounds__(256) void dwbn_kernel(
    const float* __restrict__ x, const float* __restrict__ fused,
    u16* __restrict__ yq, u16* __restrict__ ykv)
{
  __shared__ u16 Lq[64][40];
  __shared__ u16 Lk[64][40];
  int tid = threadIdx.x;
  int bb = blockIdx.z, c0 = blockIdx.y * 32, p0 = blockIdx.x * 64;
  int pl = tid & 63;
  int cg = __builtin_amdgcn_readfirstlane(tid >> 6);   // wave-uniform channel group
  int p = p0 + pl;
  int h = p / 56, w = p - h * 56;
  int roff[3], coff[3];
  float mr[3], mc[3];
#pragma unroll
  for (int d = 0; d < 3; ++d) {
    int r = h + d - 1;
    bool vr = (r >= 0) && (r < 56);
    roff[d] = (vr ? r : h) * 56;
    mr[d] = vr ? 1.f : 0.f;
    int cc = w + d - 1;
    bool vc = (cc >= 0) && (cc < 56);
    coff[d] = vc ? cc : w;
    mc[d] = vc ? 1.f : 0.f;
  }
  float m9[9];
#pragma unroll
  for (int dh = 0; dh < 3; ++dh)
#pragma unroll
    for (int dw = 0; dw < 3; ++dw) m9[dh*3+dw] = mr[dh] * mc[dw];

  __attribute__((aligned(16))) u16 oq[8], ok[8];
#pragma unroll
  for (int i = 0; i < 8; ++i) {
    int c = c0 + cg * 8 + i;
    const float* xp = x + ((size_t)bb * NDIM + c) * N_SP;
    const float* f = fused + c * 20;
    float v[9];
#pragma unroll
    for (int dh = 0; dh < 3; ++dh)
#pragma unroll
      for (int dw = 0; dw < 3; ++dw)
        v[dh*3+dw] = xp[roff[dh] + coff[dw]];
    float sq = f[9], sk = f[19];
#pragma unroll
    for (int j = 0; j < 9; ++j) {
      float xm = v[j] * m9[j];
      sq += xm * f[j];
      sk += xm * f[10+j];
    }
    oq[i] = f2bf(sq); ok[i] = f2bf(sk);
  }
  *(ushort4*)&Lq[pl][cg * 8]     = *(ushort4*)&oq[0];
  *(ushort4*)&Lq[pl][cg * 8 + 4] = *(ushort4*)&oq[4];
  *(ushort4*)&Lk[pl][cg * 8]     = *(ushort4*)&ok[0];
  *(ushort4*)&Lk[pl][cg * 8 + 4] = *(ushort4*)&ok[4];
  __syncthreads();
  int pr = tid >> 2, cc2 = (tid & 3) * 8;
  size_t g = ((size_t)bb * N_SP + p0 + pr) * NDIM + c0 + cc2;
  *(ushort4*)(yq + g)      = *(ushort4*)&Lq[pr][cc2];
  *(ushort4*)(yq + g + 4)  = *(ushort4*)&Lq[pr][cc2 + 4];
  *(ushort4*)(ykv + g)     = *(ushort4*)&Lk[pr][cc2];
  *(ushort4*)(ykv + g + 4) = *(ushort4*)&Lk[pr][cc2 + 4];
}

// ---------- MFMA GEMM: D[m][n] = sum_k A[m][k] * B[n][k]  (NT form) ----------
// 2-phase double-buffer: stage(t+1) issued BEFORE compute(t); one __syncthreads()
// per K-step (full vmcnt/lgkm drain + fence — correctness is structural). Stage
// latency overlaps the current tile's ds_read+MFMA.
// LDS k-chunk XOR swizzle (chunk ^= (row>>1)&3): g2l16 writes linearly, so the
// swizzle is applied on the per-lane GLOBAL source address and on the fragment
// read address (both-sides-or-neither, same involution).
// mode 0: LDS-transpose, store bf16 rows of n: Cout[n][m] (stride Cstride).
// mode 1: +bias, fp32 NCHW scatter (m = channel, n = bn).
struct GemmLds {
  union {
    u16 buf[2][2][128 * 32];   // [stage][A|B][row*32+k]  16KB/stage = 32KB
    u16 T[64 * 132];           // epilogue transpose chunk (16.9KB)
  } u;
};

__device__ __forceinline__ void gemm_body(GemmLds& lds, int bid,
    const u16* __restrict__ A, const u16* __restrict__ B, int Kd,
    u16* __restrict__ Cout, int Cstride,
    int mode, const float* __restrict__ bias, float* __restrict__ Out, int Mt, int Nt)
{
  int mt, nt;
  if (Nt == 8) {
    int low = bid & 7;                 // XCD slot == mt & 7
    nt = (bid >> 3) & 7;
    mt = (bid >> 6) * 8 + low;
    if (mt >= Mt) return;
  } else {
    int r = bid & 7, g = bid >> 3;
    mt = g % Mt; nt = (g / Mt) * 8 + r;
    if (nt >= Nt) return;
  }
  int m0 = mt * 128, n0 = nt * 128;

  int tid = threadIdx.x;
  int lane = tid & 63, wv = tid >> 6;
  int wm = (wv >> 1) * 64, wn = (wv & 1) * 64;
  int srow = lane >> 2;          // 0..15 (staging row within 16-row half)
  // staging source k-chunk, XOR-swizzled so linear LDS dest holds swizzled layout
  int sch = (((lane & 3) ^ ((srow >> 1) & 3))) * 8;
  int arow0 = wv * 32;           // each wave stages 32 rows of A and B
  const u16* Ag = A + (size_t)(m0 + arow0 + srow) * Kd + sch;
  const u16* Bg = B + (size_t)(n0 + arow0 + srow) * Kd + sch;

  int ml = lane & 15;
  // fragment-read k-chunk (swizzled): global chunk (lane>>4) lives at chunk^((row>>1)&3),
  // and (row>>1)&3 == (ml>>1)&3 for all fragment rows (row = base16 + ml).
  int ch = (((lane >> 4) ^ ((ml >> 1) & 3))) * 8;

  f32x4 acc[4][4];
#pragma unroll
  for (int i = 0; i < 4; ++i)
#pragma unroll
    for (int j = 0; j < 4; ++j) acc[i][j] = (f32x4){0.f, 0.f, 0.f, 0.f};

  const int nT = Kd >> 5;        // 12 (K=384) or 16 (K=512)

  auto stage = [&](int t, int s) {
    int k0 = t * 32;
    u16* Al = &lds.u.buf[s][0][arow0 * 32];
    u16* Bl = &lds.u.buf[s][1][arow0 * 32];
    g2l16(Ag + k0, Al);
    g2l16(Ag + k0 + (size_t)16 * Kd, Al + 16 * 32);
    g2l16(Bg + k0, Bl);
    g2l16(Bg + k0 + (size_t)16 * Kd, Bl + 16 * 32);
  };
  auto compute = [&](int s) {
    const u16* As = lds.u.buf[s][0];
    const u16* Bs = lds.u.buf[s][1];
    bf16x8 af[4], bfr[4];
#pragma unroll
    for (int i = 0; i < 4; ++i) {
      af[i]  = *(const bf16x8*)&As[(wm + i * 16 + ml) * 32 + ch];
      bfr[i] = *(const bf16x8*)&Bs[(wn + i * 16 + ml) * 32 + ch];
    }
#pragma unroll
    for (int i = 0; i < 4; ++i)
#pragma unroll
      for (int j = 0; j < 4; ++j)
        acc[i][j] = __builtin_amdgcn_mfma_f32_16x16x32_bf16(af[i], bfr[j], acc[i][j], 0, 0, 0);
  };

  stage(0, 0);
  __syncthreads();               // stage-0 landed (syncthreads drains vmcnt)
  int cur = 0;
  for (int t = 0; t < nT; ++t) {
    if (t + 1 < nT) stage(t + 1, cur ^ 1);   // prefetch next tile into other slot
    compute(cur);                             // overlaps the prefetch latency
    __syncthreads();                          // drain: next tile ready, reads done
    cur ^= 1;
  }
  // loop's final __syncthreads() fully drained; LDS reusable for epilogue (T union)

  if (mode == 0) {
    int q4 = (lane >> 4) * 4;
#pragma unroll
    for (int ph = 0; ph < 2; ++ph) {
      if (ph) __syncthreads();         // previous chunk's readers done
      if ((wv & 1) == ph) {            // waves whose wn == ph*64
#pragma unroll
        for (int i = 0; i < 4; ++i)
#pragma unroll
          for (int j = 0; j < 4; ++j) {
            int nl = j * 16 + ml;      // 0..63 local n
            int m = wm + i * 16 + q4;
            ushort4 o;
            o.x = f2bf(acc[i][j][0]); o.y = f2bf(acc[i][j][1]);
            o.z = f2bf(acc[i][j][2]); o.w = f2bf(acc[i][j][3]);
            *(ushort4*)&lds.u.T[nl * 132 + m] = o;
          }
      }
      __syncthreads();
#pragma unroll
      for (int it = 0; it < 4; ++it) {
        int nl = it * 16 + (tid >> 4);
        int mc = (tid & 15) * 8;
        ushort4 a = *(ushort4*)&lds.u.T[nl * 132 + mc];
        ushort4 b = *(ushort4*)&lds.u.T[nl * 132 + mc + 4];
        u16* gp = Cout + (size_t)(n0 + ph * 64 + nl) * Cstride + m0 + mc;
        *(ushort4*)gp = a;
        *(ushort4*)(gp + 4) = b;
      }
    }
  } else {
    int q4 = (lane >> 4) * 4;
#pragma unroll
    for (int i = 0; i < 4; ++i)
#pragma unroll
      for (int j = 0; j < 4; ++j) {
        int n = n0 + wn + j * 16 + ml;
        int bb = n / N_SP, p = n - bb * N_SP;
#pragma unroll
        for (int rr = 0; rr < 4; ++rr) {
          int m = m0 + wm + i * 16 + q4 + rr;
          Out[((size_t)bb * NDIM + m) * N_SP + p] = acc[i][j][rr] + bias[m];
        }
      }
  }
}

__global__ __launch_bounds__(256) void mfma_gemm(
    const u16* __restrict__ A, const u16* __restrict__ B, int Kd,
    u16* __restrict__ Cout, int Cstride,
    int mode, const float* __restrict__ bias, float* __restrict__ Out, int Mt, int Nt)
{
  __shared__ GemmLds lds;
  gemm_body(lds, blockIdx.x, A, B, Kd, Cout, Cstride, mode, bias, Out, Mt, Nt);
}

// Q GEMM (800 blocks) + KV GEMM (1600 blocks) in ONE launch: tail of Q fills with
// head of KV. Offset 800 is 0 mod 8 so KV's bid&7 <-> XCD association is preserved.
__global__ __launch_bounds__(256) void mfma_gemm_qkv(
    const u16* __restrict__ Wq, const u16* __restrict__ yq, u16* __restrict__ Qb,
    const u16* __restrict__ ykv, const u16* __restrict__ Wkv, u16* __restrict__ KVb)
{
  __shared__ GemmLds lds;
  int bid = blockIdx.x;
  if (bid < 800)
    gemm_body(lds, bid, Wq, yq, NDIM, Qb, NINNER, 0, nullptr, nullptr, 4, 196);
  else
    gemm_body(lds, bid - 800, ykv, Wkv, NDIM, KVb, BNCOL, 0, nullptr, nullptr, 196, 8);
}

// ---------- merged: ktv (448 blocks, longer -> dispatched first) + diag (784 blocks) ----------
// ktv[bh][d][e] = sum_p K[d][p] V[e][p]   (MFMA frags direct from global, 7-way atomic accum)
// diag[h][bn]   = SCALE * sum_d Q[bn][d] K[d][bn] ; m0 = sum   (dg (h,bn): coalesced)
__global__ __launch_bounds__(256) void diag_ktv_kernel(
    const u16* __restrict__ Q, const u16* __restrict__ KV,
    float* __restrict__ dg, float* __restrict__ m0, float* __restrict__ ktv)
{
  __shared__ float wsum[4];
  int bid = blockIdx.x, tid = threadIdx.x;
  if (bid < 448) {
    // ---- ktv: bh = bid/7 owns cols [xb*448, xb*448+448) of batch bb ----
    int bh = bid / 7, xb = bid - bh * 7;
    int bb = bh >> 3, hh = bh & 7;
    int w = tid >> 6, lane = tid & 63;
    int ml = lane & 15, quad = lane >> 4, q8 = quad * 8;
    size_t colbase = (size_t)bb * N_SP + xb * 448 + q8;
    const u16* Ar = KV + (size_t)(hh * 64 + w * 16 + ml) * BNCOL + colbase;
    const u16* Br = KV + (size_t)(NINNER + hh * 64 + ml) * BNCOL + colbase;
    f32x4 acc[4];
#pragma unroll
    for (int j = 0; j < 4; ++j) acc[j] = (f32x4){0.f, 0.f, 0.f, 0.f};
#pragma unroll
    for (int t = 0; t < 14; ++t) {
      int po = t * 32;
      bf16x8 a = *(const bf16x8*)(Ar + po);
#pragma unroll
      for (int j = 0; j < 4; ++j) {
        bf16x8 b = *(const bf16x8*)(Br + (size_t)j * 16 * BNCOL + po);
        acc[j] = __builtin_amdgcn_mfma_f32_16x16x32_bf16(a, b, acc[j], 0, 0, 0);
      }
    }
    float* kt = ktv + bh * 4096;
#pragma unroll
    for (int j = 0; j < 4; ++j)
#pragma unroll
      for (int r = 0; r < 4; ++r)
        atomicAdd(&kt[(w * 16 + quad * 4 + r) * 64 + j * 16 + ml], acc[j][r]);
  } else {
    // ---- diag ----
    int b2 = bid - 448;
    int hh = b2 / 98, xb = b2 - hh * 98;
    int bn = xb * 256 + tid;
    const u16* qrow = Q + (size_t)bn * NINNER + hh * 64;
    const u16* kcol = KV + (size_t)(hh * 64) * BNCOL + bn;
    float s = 0.f;
#pragma unroll
    for (int d0 = 0; d0 < 64; d0 += 8) {
      ushort4 a = *(const ushort4*)(qrow + d0);
      ushort4 b = *(const ushort4*)(qrow + d0 + 4);
      const u16* kp = kcol + (size_t)d0 * BNCOL;
      s += bf2f(a.x) * bf2f(kp[0]);
      s += bf2f(a.y) * bf2f(kp[(size_t)1 * BNCOL]);
      s += bf2f(a.z) * bf2f(kp[(size_t)2 * BNCOL]);
      s += bf2f(a.w) * bf2f(kp[(size_t)3 * BNCOL]);
      s += bf2f(b.x) * bf2f(kp[(size_t)4 * BNCOL]);
      s += bf2f(b.y) * bf2f(kp[(size_t)5 * BNCOL]);
      s += bf2f(b.z) * bf2f(kp[(size_t)6 * BNCOL]);
      s += bf2f(b.w) * bf2f(kp[(size_t)7 * BNCOL]);
    }
    s *= SCALE_F;
    dg[(size_t)hh * BNCOL + bn] = s;     // (h, bn): coalesced
    float r = s;
#pragma unroll
    for (int off = 32; off > 0; off >>= 1) r += __shfl_down(r, off);
    if ((tid & 63) == 0) wsum[tid >> 6] = r;
    __syncthreads();
    if (tid == 0) atomicAdd(m0, wsum[0] + wsum[1] + wsum[2] + wsum[3]);
  }
}

// ---------- out[p][e] = (m0 - diag[p])*V[e][p] + SCALE * sum_d Q[p][d]*ktv[d][e] ----------
// MFMA: A = Q rows (global), B = ktv^T bf16 (LDS). Output (bn, c) via LDS transpose.
__global__ __launch_bounds__(256) void attn_out_kernel(
    const u16* __restrict__ Q, const u16* __restrict__ KV,
    const float* __restrict__ dg, const float* __restrict__ ktv,
    const float* __restrict__ m0p, u16* __restrict__ OutA)
{
  __shared__ u16 Bt[64][72];    // ktv^T [e][d] bf16
  __shared__ u16 T2[64][72];    // out transpose [p][e]
  __shared__ float ds2[64];
  int bh = blockIdx.y, bb = bh >> 3, hh = bh & 7;
  int p0 = blockIdx.x * 64;
  int tid = threadIdx.x;
  const float* kt = ktv + bh * 4096;
  for (int l = tid; l < 4096; l += 256) {
    int d = l >> 6, e = l & 63;
    Bt[e][d] = f2bf(kt[l]);
  }
  if (tid < 64) ds2[tid] = dg[(size_t)hh * BNCOL + bb * N_SP + p0 + tid];
  __syncthreads();
  int w = tid >> 6, lane = tid & 63;
  int ml = lane & 15, quad = lane >> 4, q8 = quad * 8;
  const u16* Ar = Q + ((size_t)bb * N_SP + p0 + w * 16 + ml) * NINNER + hh * 64 + q8;
  bf16x8 a0 = *(const bf16x8*)Ar;
  bf16x8 a1 = *(const bf16x8*)(Ar + 32);
  f32x4 acc[4];
#pragma unroll
  for (int j = 0; j < 4; ++j) acc[j] = (f32x4){0.f, 0.f, 0.f, 0.f};
#pragma unroll
  for (int j = 0; j < 4; ++j) {
    bf16x8 b0 = *(const bf16x8*)&Bt[j * 16 + ml][q8];
    bf16x8 b1 = *(const bf16x8*)&Bt[j * 16 + ml][32 + q8];
    acc[j] = __builtin_amdgcn_mfma_f32_16x16x32_bf16(a0, b0, acc[j], 0, 0, 0);
    acc[j] = __builtin_amdgcn_mfma_f32_16x16x32_bf16(a1, b1, acc[j], 0, 0, 0);
  }
  float m0v = *m0p;
  size_t pcol = (size_t)bb * N_SP + p0 + w * 16 + quad * 4;
#pragma unroll
  for (int j = 0; j < 4; ++j) {
    const u16* vr = KV + (size_t)(NINNER + hh * 64 + j * 16 + ml) * BNCOL + pcol;
    ushort4 vv = *(const ushort4*)vr;
    const u16* vp = (const u16*)&vv;
#pragma unroll
    for (int r = 0; r < 4; ++r) {
      float dvm = m0v - ds2[w * 16 + quad * 4 + r];
      float o = SCALE_F * acc[j][r] + dvm * bf2f(vp[r]);
      T2[w * 16 + quad * 4 + r][j * 16 + ml] = f2bf(o);
    }
  }
  __syncthreads();
  int pl = tid >> 2, ec = (tid & 3) * 16;
  u16* gp = OutA + ((size_t)bb * N_SP + p0 + pl) * NINNER + hh * 64 + ec;
  *(ushort4*)gp        = *(ushort4*)&T2[pl][ec];
  *(ushort4*)(gp + 4)  = *(ushort4*)&T2[pl][ec + 4];
  *(ushort4*)(gp + 8)  = *(ushort4*)&T2[pl][ec + 8];
  *(ushort4*)(gp + 12) = *(ushort4*)&T2[pl][ec + 12];
}

extern "C" void kernel_launch(void* const* d_in, const int* in_sizes, int n_in,
                              void* d_out, int out_size, void* d_ws, size_t ws_size,
                              hipStream_t stream)
{
  (void)in_sizes; (void)n_in; (void)out_size; (void)ws_size;
  const float* x      = (const float*)d_in[0];
  const float* wq_dw  = (const float*)d_in[1];
  const float* wq_g   = (const float*)d_in[2];
  const float* wq_b   = (const float*)d_in[3];
  const float* wq_m   = (const float*)d_in[4];
  const float* wq_v   = (const float*)d_in[5];
  const float* wq_pw  = (const float*)d_in[6];
  const float* wkv_dw = (const float*)d_in[7];
  const float* wkv_g  = (const float*)d_in[8];
  const float* wkv_b  = (const float*)d_in[9];
  const float* wkv_m  = (const float*)d_in[10];
  const float* wkv_v  = (const float*)d_in[11];
  const float* wkv_pw = (const float*)d_in[12];
  const float* wo     = (const float*)d_in[13];
  const float* bo     = (const float*)d_in[14];
  float* out = (float*)d_out;

  char* ws = (char*)d_ws;
  size_t off = 0;
  auto alloc = [&](size_t bytes) {
    void* p = ws + off; off = (off + bytes + 255) & ~(size_t)255; return p;
  };
  u16* yq   = (u16*)alloc((size_t)BNCOL * NDIM * 2);        // 19.27 MB  (BN, 384)
  u16* ykv  = (u16*)alloc((size_t)BNCOL * NDIM * 2);        // 19.27 MB  (BN, 384)
  u16* Qb   = (u16*)alloc((size_t)BNCOL * NINNER * 2);      // 25.69 MB  (BN, 512)
  u16* KVb  = (u16*)alloc((size_t)2 * NINNER * BNCOL * 2);  // 51.38 MB  (1024, BN): K rows 0..511, V rows 512..1023
  float* dgb  = (float*)alloc((size_t)BNCOL * 8 * 4);       // 0.80 MB   (h, bn)
  float* ktvb = (float*)alloc((size_t)64 * 4096 * 4 + 64);  // 1.05 MB (+m0 tail)
  u16* Wq  = (u16*)alloc((size_t)NINNER * NDIM * 2);        // 0.39 MB
  u16* Wkv = (u16*)alloc((size_t)2 * NINNER * NDIM * 2);    // 0.79 MB
  u16* Wo  = (u16*)alloc((size_t)NDIM * NINNER * 2);        // 0.39 MB
  float* fused = (float*)alloc((size_t)NDIM * 20 * 4);      // 30.7 KB BN-folded dw weights
  float* m0 = ktvb + 64 * 4096;
  u16* OutA = yq;   // alias: yq/ykv dead after the pw GEMMs; 25.7 MB fits in their 38.5 MB

  hipMemsetAsync(ktvb, 0, (size_t)64 * 4096 * 4 + 4, stream);

  cvt_kernel<<<1536, 256, 0, stream>>>(wq_pw, wkv_pw, wo, Wq, Wkv, Wo,
                                       wq_dw, wq_g, wq_b, wq_m, wq_v,
                                       wkv_dw, wkv_g, wkv_b, wkv_m, wkv_v, fused);

  dwbn_kernel<<<dim3(49, 12, 8), 256, 0, stream>>>(x, fused, yq, ykv);

  // Q (A=Wq, B=yq -> Qb) + KV swapped (A=ykv, B=Wkv -> KVb) in one launch
  mfma_gemm_qkv<<<dim3(800 + 1600), 256, 0, stream>>>(Wq, yq, Qb, ykv, Wkv, KVb);

  // ktv (448 blocks) + diag (784 blocks) in one launch
  diag_ktv_kernel<<<dim3(448 + 784), 256, 0, stream>>>(Qb, KVb, dgb, m0, ktvb);

  attn_out_kernel<<<dim3(49, 64), 256, 0, stream>>>(Qb, KVb, dgb, ktvb, m0, OutA);

  mfma_gemm<<<dim3(3 * 200), 256, 0, stream>>>(Wo, OutA, NINNER, nullptr, 0, 1, bo, out, 3, 196);
}

// Round 11
// 242.938 us; speedup vs baseline: 1.2309x; 1.1420x over previous
//
#include <hip/hip_runtime.h>

typedef unsigned short u16;

#define N_SP   3136     // 56*56
#define BNCOL  25088    // B * N_SP
#define NDIM   384
#define NINNER 512
#define SCALE_F 0.125f

typedef __attribute__((ext_vector_type(8))) short bf16x8;
typedef __attribute__((ext_vector_type(4))) float f32x4;

#define AS1 __attribute__((address_space(1)))
#define AS3 __attribute__((address_space(3)))

__device__ __forceinline__ float bf2f(u16 u) {
  union { unsigned int i; float f; } v; v.i = ((unsigned int)u) << 16; return v.f;
}
__device__ __forceinline__ u16 f2bf(float f) {
  union { float f; unsigned int i; } v; v.f = f;
  unsigned int r = v.i + 0x7fffu + ((v.i >> 16) & 1u);   // RNE
  return (u16)(r >> 16);
}

// async global->LDS, 16B per lane. lds base must be wave-uniform; lane i lands at lds + i*16B.
__device__ __forceinline__ void g2l16(const u16* g, u16* l) {
  __builtin_amdgcn_global_load_lds((const AS1 unsigned int*)g,
                                   (AS3 unsigned int*)l, 16, 0, 0);
}

// ---------- weight fp32 -> bf16 convert + BN-folded depthwise weights ----------
__global__ __launch_bounds__(256) void cvt_kernel(
    const float* __restrict__ a, const float* __restrict__ b, const float* __restrict__ c,
    u16* __restrict__ oa, u16* __restrict__ ob, u16* __restrict__ oc,
    const float* __restrict__ qdw, const float* __restrict__ qg, const float* __restrict__ qb2,
    const float* __restrict__ qm,  const float* __restrict__ qv,
    const float* __restrict__ kdw, const float* __restrict__ kg, const float* __restrict__ kb2,
    const float* __restrict__ km,  const float* __restrict__ kvv,
    float* __restrict__ fused)
{
  int i = blockIdx.x * 256 + threadIdx.x;
  if (i < 196608) oa[i] = f2bf(a[i]);
  ob[i] = f2bf(b[i]);               // grid sized exactly to 393216
  if (i < 196608) oc[i] = f2bf(c[i]);
  if (i < NDIM) {
    float invq = qg[i] * rsqrtf(qv[i] + 1e-5f);
    float invk = kg[i] * rsqrtf(kvv[i] + 1e-5f);
    float* f = fused + i * 20;
#pragma unroll
    for (int j = 0; j < 9; ++j) { f[j] = qdw[i*9+j] * invq; f[10+j] = kdw[i*9+j] * invk; }
    f[9]  = qb2[i] - qm[i] * invq;
    f[19] = kb2[i] - km[i] * invk;
  }
}

// ---------- fused depthwise 3x3 conv + BN (q and kv paths), output (BN, C) bf16 ----------
__global__ __launch_bounds__(256) void dwbn_kernel(
    const float* __restrict__ x, const float* __restrict__ fused,
    u16* __restrict__ yq, u16* __restrict__ ykv)
{
  __shared__ u16 Lq[64][40];
  __shared__ u16 Lk[64][40];
  int tid = threadIdx.x;
  int bb = blockIdx.z, c0 = blockIdx.y * 32, p0 = blockIdx.x * 64;
  int pl = tid & 63;
  int cg = __builtin_amdgcn_readfirstlane(tid >> 6);   // wave-uniform channel group
  int p = p0 + pl;
  int h = p / 56, w = p - h * 56;
  int roff[3], coff[3];
  float mr[3], mc[3];
#pragma unroll
  for (int d = 0; d < 3; ++d) {
    int r = h + d - 1;
    bool vr = (r >= 0) && (r < 56);
    roff[d] = (vr ? r : h) * 56;
    mr[d] = vr ? 1.f : 0.f;
    int cc = w + d - 1;
    bool vc = (cc >= 0) && (cc < 56);
    coff[d] = vc ? cc : w;
    mc[d] = vc ? 1.f : 0.f;
  }
  float m9[9];
#pragma unroll
  for (int dh = 0; dh < 3; ++dh)
#pragma unroll
    for (int dw = 0; dw < 3; ++dw) m9[dh*3+dw] = mr[dh] * mc[dw];

  __attribute__((aligned(16))) u16 oq[8], ok[8];
#pragma unroll
  for (int i = 0; i < 8; ++i) {
    int c = c0 + cg * 8 + i;
    const float* xp = x + ((size_t)bb * NDIM + c) * N_SP;
    const float* f = fused + c * 20;
    float v[9];
#pragma unroll
    for (int dh = 0; dh < 3; ++dh)
#pragma unroll
      for (int dw = 0; dw < 3; ++dw)
        v[dh*3+dw] = xp[roff[dh] + coff[dw]];
    float sq = f[9], sk = f[19];
#pragma unroll
    for (int j = 0; j < 9; ++j) {
      float xm = v[j] * m9[j];
      sq += xm * f[j];
      sk += xm * f[10+j];
    }
    oq[i] = f2bf(sq); ok[i] = f2bf(sk);
  }
  *(ushort4*)&Lq[pl][cg * 8]     = *(ushort4*)&oq[0];
  *(ushort4*)&Lq[pl][cg * 8 + 4] = *(ushort4*)&oq[4];
  *(ushort4*)&Lk[pl][cg * 8]     = *(ushort4*)&ok[0];
  *(ushort4*)&Lk[pl][cg * 8 + 4] = *(ushort4*)&ok[4];
  __syncthreads();
  int pr = tid >> 2, cc2 = (tid & 3) * 8;
  size_t g = ((size_t)bb * N_SP + p0 + pr) * NDIM + c0 + cc2;
  *(ushort4*)(yq + g)      = *(ushort4*)&Lq[pr][cc2];
  *(ushort4*)(yq + g + 4)  = *(ushort4*)&Lq[pr][cc2 + 4];
  *(ushort4*)(ykv + g)     = *(ushort4*)&Lk[pr][cc2];
  *(ushort4*)(ykv + g + 4) = *(ushort4*)&Lk[pr][cc2 + 4];
}

// ---------- MFMA GEMM: D[m][n] = sum_k A[m][k] * B[n][k]  (NT form) ----------
// 2-phase double-buffer (VERIFIED R8), BK=64: stage(t+1) issued BEFORE compute(t);
// one __syncthreads() per K-step. BK 32->64 halves the number of full drains
// (13 -> 7 for K=384) and doubles the MFMA work covering each prefetch.
// LDS k-chunk XOR swizzle, BK=64 geometry: key = row&7 over 8 chunks of 8 u16.
//   stage: lane L covers row (L>>3), chunk (L&7) of an 8-row slab; source chunk
//          = (L&7) ^ (L>>3)  (slab base multiple of 8 -> row&7 == L>>3).
//   read:  global chunk g lives at LDS chunk g ^ (ml&7) (frag rows = base16+ml).
// Involution both sides; 8 lanes/16B-chunk-slot at distinct rows = all 32 banks
// at the structural floor — isomorphic to R8's measured-0-conflict pattern.
// mode 0: LDS-transpose, store bf16 rows of n: Cout[n][m] (stride Cstride).
// mode 1: +bias, fp32 NCHW scatter (m = channel, n = bn).
struct GemmLds {
  union {
    u16 buf[2][2][128 * 64];   // [stage][A|B][row*64+k]  32KB/stage = 64KB
    u16 T[64 * 132];           // epilogue transpose chunk (16.9KB)
  } u;
};

__device__ __forceinline__ void gemm_body(GemmLds& lds, int bid,
    const u16* __restrict__ A, const u16* __restrict__ B, int Kd,
    u16* __restrict__ Cout, int Cstride,
    int mode, const float* __restrict__ bias, float* __restrict__ Out, int Mt, int Nt)
{
  int mt, nt;
  if (Nt == 8) {
    int low = bid & 7;                 // XCD slot == mt & 7
    nt = (bid >> 3) & 7;
    mt = (bid >> 6) * 8 + low;
    if (mt >= Mt) return;
  } else {
    int r = bid & 7, g = bid >> 3;
    mt = g % Mt; nt = (g / Mt) * 8 + r;
    if (nt >= Nt) return;
  }
  int m0 = mt * 128, n0 = nt * 128;

  int tid = threadIdx.x;
  int lane = tid & 63, wv = tid >> 6;
  int wm = (wv >> 1) * 64, wn = (wv & 1) * 64;
  int srow8 = lane >> 3;                 // 0..7 (row within 8-row staging slab)
  int sc8 = ((lane & 7) ^ srow8) * 8;    // XOR-swizzled source k-chunk
  int arow0 = wv * 32;                   // each wave stages 32 rows of A and B
  const u16* Ag = A + (size_t)(m0 + arow0 + srow8) * Kd + sc8;
  const u16* Bg = B + (size_t)(n0 + arow0 + srow8) * Kd + sc8;

  int ml = lane & 15;
  int quad = lane >> 4;
  // read chunk offsets (u16) for the two 32-k halves of a 64-k step
  int chk0 = ((quad)     ^ (ml & 7)) * 8;
  int chk1 = ((quad + 4) ^ (ml & 7)) * 8;

  f32x4 acc[4][4];
#pragma unroll
  for (int i = 0; i < 4; ++i)
#pragma unroll
    for (int j = 0; j < 4; ++j) acc[i][j] = (f32x4){0.f, 0.f, 0.f, 0.f};

  const int nT = Kd >> 6;        // 6 (K=384) or 8 (K=512)

  auto stage = [&](int t, int s) {
    int k0 = t * 64;
    u16* Al = &lds.u.buf[s][0][arow0 * 64];
    u16* Bl = &lds.u.buf[s][1][arow0 * 64];
#pragma unroll
    for (int j = 0; j < 4; ++j) {        // 4 slabs of 8 rows
      g2l16(Ag + k0 + (size_t)(8 * j) * Kd, Al + j * 8 * 64);
      g2l16(Bg + k0 + (size_t)(8 * j) * Kd, Bl + j * 8 * 64);
    }
  };
  auto compute = [&](int s) {
    const u16* As = lds.u.buf[s][0];
    const u16* Bs = lds.u.buf[s][1];
    bf16x8 af[4], bfr[4];
    // half 0 (k 0..31 of the step)
#pragma unroll
    for (int i = 0; i < 4; ++i) {
      af[i]  = *(const bf16x8*)&As[(wm + i * 16 + ml) * 64 + chk0];
      bfr[i] = *(const bf16x8*)&Bs[(wn + i * 16 + ml) * 64 + chk0];
    }
#pragma unroll
    for (int i = 0; i < 4; ++i)
#pragma unroll
      for (int j = 0; j < 4; ++j)
        acc[i][j] = __builtin_amdgcn_mfma_f32_16x16x32_bf16(af[i], bfr[j], acc[i][j], 0, 0, 0);
    // half 1 (k 32..63)
#pragma unroll
    for (int i = 0; i < 4; ++i) {
      af[i]  = *(const bf16x8*)&As[(wm + i * 16 + ml) * 64 + chk1];
      bfr[i] = *(const bf16x8*)&Bs[(wn + i * 16 + ml) * 64 + chk1];
    }
#pragma unroll
    for (int i = 0; i < 4; ++i)
#pragma unroll
      for (int j = 0; j < 4; ++j)
        acc[i][j] = __builtin_amdgcn_mfma_f32_16x16x32_bf16(af[i], bfr[j], acc[i][j], 0, 0, 0);
  };

  stage(0, 0);
  __syncthreads();               // stage-0 landed (syncthreads drains vmcnt)
  int cur = 0;
  for (int t = 0; t < nT; ++t) {
    if (t + 1 < nT) stage(t + 1, cur ^ 1);   // prefetch next tile into other slot
    compute(cur);                             // overlaps the prefetch latency
    __syncthreads();                          // drain: next tile ready, reads done
    cur ^= 1;
  }
  // loop's final __syncthreads() fully drained; LDS reusable for epilogue (T union)

  if (mode == 0) {
    int q4 = (lane >> 4) * 4;
#pragma unroll
    for (int ph = 0; ph < 2; ++ph) {
      if (ph) __syncthreads();         // previous chunk's readers done
      if ((wv & 1) == ph) {            // waves whose wn == ph*64
#pragma unroll
        for (int i = 0; i < 4; ++i)
#pragma unroll
          for (int j = 0; j < 4; ++j) {
            int nl = j * 16 + ml;      // 0..63 local n
            int m = wm + i * 16 + q4;
            ushort4 o;
            o.x = f2bf(acc[i][j][0]); o.y = f2bf(acc[i][j][1]);
            o.z = f2bf(acc[i][j][2]); o.w = f2bf(acc[i][j][3]);
            *(ushort4*)&lds.u.T[nl * 132 + m] = o;
          }
      }
      __syncthreads();
#pragma unroll
      for (int it = 0; it < 4; ++it) {
        int nl = it * 16 + (tid >> 4);
        int mc = (tid & 15) * 8;
        ushort4 a = *(ushort4*)&lds.u.T[nl * 132 + mc];
        ushort4 b = *(ushort4*)&lds.u.T[nl * 132 + mc + 4];
        u16* gp = Cout + (size_t)(n0 + ph * 64 + nl) * Cstride + m0 + mc;
        *(ushort4*)gp = a;
        *(ushort4*)(gp + 4) = b;
      }
    }
  } else {
    int q4 = (lane >> 4) * 4;
#pragma unroll
    for (int i = 0; i < 4; ++i)
#pragma unroll
      for (int j = 0; j < 4; ++j) {
        int n = n0 + wn + j * 16 + ml;
        int bb = n / N_SP, p = n - bb * N_SP;
#pragma unroll
        for (int rr = 0; rr < 4; ++rr) {
          int m = m0 + wm + i * 16 + q4 + rr;
          Out[((size_t)bb * NDIM + m) * N_SP + p] = acc[i][j][rr] + bias[m];
        }
      }
  }
}

__global__ __launch_bounds__(256) void mfma_gemm(
    const u16* __restrict__ A, const u16* __restrict__ B, int Kd,
    u16* __restrict__ Cout, int Cstride,
    int mode, const float* __restrict__ bias, float* __restrict__ Out, int Mt, int Nt)
{
  __shared__ GemmLds lds;
  gemm_body(lds, blockIdx.x, A, B, Kd, Cout, Cstride, mode, bias, Out, Mt, Nt);
}

// Q GEMM (800 blocks) + KV GEMM (1600 blocks) in ONE launch: tail of Q fills with
// head of KV. Offset 800 is 0 mod 8 so KV's bid&7 <-> XCD association is preserved.
__global__ __launch_bounds__(256) void mfma_gemm_qkv(
    const u16* __restrict__ Wq, const u16* __restrict__ yq, u16* __restrict__ Qb,
    const u16* __restrict__ ykv, const u16* __restrict__ Wkv, u16* __restrict__ KVb)
{
  __shared__ GemmLds lds;
  int bid = blockIdx.x;
  if (bid < 800)
    gemm_body(lds, bid, Wq, yq, NDIM, Qb, NINNER, 0, nullptr, nullptr, 4, 196);
  else
    gemm_body(lds, bid - 800, ykv, Wkv, NDIM, KVb, BNCOL, 0, nullptr, nullptr, 196, 8);
}

// ---------- merged: ktv (448 blocks, longer -> dispatched first) + diag (784 blocks) ----------
// ktv[bh][d][e] = sum_p K[d][p] V[e][p]   (MFMA frags direct from global, 7-way atomic accum)
// diag[h][bn]   = SCALE * sum_d Q[bn][d] K[d][bn] ; m0 = sum   (dg (h,bn): coalesced)
__global__ __launch_bounds__(256) void diag_ktv_kernel(
    const u16* __restrict__ Q, const u16* __restrict__ KV,
    float* __restrict__ dg, float* __restrict__ m0, float* __restrict__ ktv)
{
  __shared__ float wsum[4];
  int bid = blockIdx.x, tid = threadIdx.x;
  if (bid < 448) {
    // ---- ktv: bh = bid/7 owns cols [xb*448, xb*448+448) of batch bb ----
    int bh = bid / 7, xb = bid - bh * 7;
    int bb = bh >> 3, hh = bh & 7;
    int w = tid >> 6, lane = tid & 63;
    int ml = lane & 15, quad = lane >> 4, q8 = quad * 8;
    size_t colbase = (size_t)bb * N_SP + xb * 448 + q8;
    const u16* Ar = KV + (size_t)(hh * 64 + w * 16 + ml) * BNCOL + colbase;
    const u16* Br = KV + (size_t)(NINNER + hh * 64 + ml) * BNCOL + colbase;
    f32x4 acc[4];
#pragma unroll
    for (int j = 0; j < 4; ++j) acc[j] = (f32x4){0.f, 0.f, 0.f, 0.f};
#pragma unroll
    for (int t = 0; t < 14; ++t) {
      int po = t * 32;
      bf16x8 a = *(const bf16x8*)(Ar + po);
#pragma unroll
      for (int j = 0; j < 4; ++j) {
        bf16x8 b = *(const bf16x8*)(Br + (size_t)j * 16 * BNCOL + po);
        acc[j] = __builtin_amdgcn_mfma_f32_16x16x32_bf16(a, b, acc[j], 0, 0, 0);
      }
    }
    float* kt = ktv + bh * 4096;
#pragma unroll
    for (int j = 0; j < 4; ++j)
#pragma unroll
      for (int r = 0; r < 4; ++r)
        atomicAdd(&kt[(w * 16 + quad * 4 + r) * 64 + j * 16 + ml], acc[j][r]);
  } else {
    // ---- diag ----
    int b2 = bid - 448;
    int hh = b2 / 98, xb = b2 - hh * 98;
    int bn = xb * 256 + tid;
    const u16* qrow = Q + (size_t)bn * NINNER + hh * 64;
    const u16* kcol = KV + (size_t)(hh * 64) * BNCOL + bn;
    float s = 0.f;
#pragma unroll
    for (int d0 = 0; d0 < 64; d0 += 8) {
      ushort4 a = *(const ushort4*)(qrow + d0);
      ushort4 b = *(const ushort4*)(qrow + d0 + 4);
      const u16* kp = kcol + (size_t)d0 * BNCOL;
      s += bf2f(a.x) * bf2f(kp[0]);
      s += bf2f(a.y) * bf2f(kp[(size_t)1 * BNCOL]);
      s += bf2f(a.z) * bf2f(kp[(size_t)2 * BNCOL]);
      s += bf2f(a.w) * bf2f(kp[(size_t)3 * BNCOL]);
      s += bf2f(b.x) * bf2f(kp[(size_t)4 * BNCOL]);
      s += bf2f(b.y) * bf2f(kp[(size_t)5 * BNCOL]);
      s += bf2f(b.z) * bf2f(kp[(size_t)6 * BNCOL]);
      s += bf2f(b.w) * bf2f(kp[(size_t)7 * BNCOL]);
    }
    s *= SCALE_F;
    dg[(size_t)hh * BNCOL + bn] = s;     // (h, bn): coalesced
    float r = s;
#pragma unroll
    for (int off = 32; off > 0; off >>= 1) r += __shfl_down(r, off);
    if ((tid & 63) == 0) wsum[tid >> 6] = r;
    __syncthreads();
    if (tid == 0) atomicAdd(m0, wsum[0] + wsum[1] + wsum[2] + wsum[3]);
  }
}

// ---------- out[p][e] = (m0 - diag[p])*V[e][p] + SCALE * sum_d Q[p][d]*ktv[d][e] ----------
// MFMA: A = Q rows (global), B = ktv^T bf16 (LDS). Output (bn, c) via LDS transpose.
__global__ __launch_bounds__(256) void attn_out_kernel(
    const u16* __restrict__ Q, const u16* __restrict__ KV,
    const float* __restrict__ dg, const float* __restrict__ ktv,
    const float* __restrict__ m0p, u16* __restrict__ OutA)
{
  __shared__ u16 Bt[64][72];    // ktv^T [e][d] bf16
  __shared__ u16 T2[64][72];    // out transpose [p][e]
  __shared__ float ds2[64];
  int bh = blockIdx.y, bb = bh >> 3, hh = bh & 7;
  int p0 = blockIdx.x * 64;
  int tid = threadIdx.x;
  const float* kt = ktv + bh * 4096;
  for (int l = tid; l < 4096; l += 256) {
    int d = l >> 6, e = l & 63;
    Bt[e][d] = f2bf(kt[l]);
  }
  if (tid < 64) ds2[tid] = dg[(size_t)hh * BNCOL + bb * N_SP + p0 + tid];
  __syncthreads();
  int w = tid >> 6, lane = tid & 63;
  int ml = lane & 15, quad = lane >> 4, q8 = quad * 8;
  const u16* Ar = Q + ((size_t)bb * N_SP + p0 + w * 16 + ml) * NINNER + hh * 64 + q8;
  bf16x8 a0 = *(const bf16x8*)Ar;
  bf16x8 a1 = *(const bf16x8*)(Ar + 32);
  f32x4 acc[4];
#pragma unroll
  for (int j = 0; j < 4; ++j) acc[j] = (f32x4){0.f, 0.f, 0.f, 0.f};
#pragma unroll
  for (int j = 0; j < 4; ++j) {
    bf16x8 b0 = *(const bf16x8*)&Bt[j * 16 + ml][q8];
    bf16x8 b1 = *(const bf16x8*)&Bt[j * 16 + ml][32 + q8];
    acc[j] = __builtin_amdgcn_mfma_f32_16x16x32_bf16(a0, b0, acc[j], 0, 0, 0);
    acc[j] = __builtin_amdgcn_mfma_f32_16x16x32_bf16(a1, b1, acc[j], 0, 0, 0);
  }
  float m0v = *m0p;
  size_t pcol = (size_t)bb * N_SP + p0 + w * 16 + quad * 4;
#pragma unroll
  for (int j = 0; j < 4; ++j) {
    const u16* vr = KV + (size_t)(NINNER + hh * 64 + j * 16 + ml) * BNCOL + pcol;
    ushort4 vv = *(const ushort4*)vr;
    const u16* vp = (const u16*)&vv;
#pragma unroll
    for (int r = 0; r < 4; ++r) {
      float dvm = m0v - ds2[w * 16 + quad * 4 + r];
      float o = SCALE_F * acc[j][r] + dvm * bf2f(vp[r]);
      T2[w * 16 + quad * 4 + r][j * 16 + ml] = f2bf(o);
    }
  }
  __syncthreads();
  int pl = tid >> 2, ec = (tid & 3) * 16;
  u16* gp = OutA + ((size_t)bb * N_SP + p0 + pl) * NINNER + hh * 64 + ec;
  *(ushort4*)gp        = *(ushort4*)&T2[pl][ec];
  *(ushort4*)(gp + 4)  = *(ushort4*)&T2[pl][ec + 4];
  *(ushort4*)(gp + 8)  = *(ushort4*)&T2[pl][ec + 8];
  *(ushort4*)(gp + 12) = *(ushort4*)&T2[pl][ec + 12];
}

extern "C" void kernel_launch(void* const* d_in, const int* in_sizes, int n_in,
                              void* d_out, int out_size, void* d_ws, size_t ws_size,
                              hipStream_t stream)
{
  (void)in_sizes; (void)n_in; (void)out_size; (void)ws_size;
  const float* x      = (const float*)d_in[0];
  const float* wq_dw  = (const float*)d_in[1];
  const float* wq_g   = (const float*)d_in[2];
  const float* wq_b   = (const float*)d_in[3];
  const float* wq_m   = (const float*)d_in[4];
  const float* wq_v   = (const float*)d_in[5];
  const float* wq_pw  = (const float*)d_in[6];
  const float* wkv_dw = (const float*)d_in[7];
  const float* wkv_g  = (const float*)d_in[8];
  const float* wkv_b  = (const float*)d_in[9];
  const float* wkv_m  = (const float*)d_in[10];
  const float* wkv_v  = (const float*)d_in[11];
  const float* wkv_pw = (const float*)d_in[12];
  const float* wo     = (const float*)d_in[13];
  const float* bo     = (const float*)d_in[14];
  float* out = (float*)d_out;

  char* ws = (char*)d_ws;
  size_t off = 0;
  auto alloc = [&](size_t bytes) {
    void* p = ws + off; off = (off + bytes + 255) & ~(size_t)255; return p;
  };
  u16* yq   = (u16*)alloc((size_t)BNCOL * NDIM * 2);        // 19.27 MB  (BN, 384)
  u16* ykv  = (u16*)alloc((size_t)BNCOL * NDIM * 2);        // 19.27 MB  (BN, 384)
  u16* Qb   = (u16*)alloc((size_t)BNCOL * NINNER * 2);      // 25.69 MB  (BN, 512)
  u16* KVb  = (u16*)alloc((size_t)2 * NINNER * BNCOL * 2);  // 51.38 MB  (1024, BN): K rows 0..511, V rows 512..1023
  float* dgb  = (float*)alloc((size_t)BNCOL * 8 * 4);       // 0.80 MB   (h, bn)
  float* ktvb = (float*)alloc((size_t)64 * 4096 * 4 + 64);  // 1.05 MB (+m0 tail)
  u16* Wq  = (u16*)alloc((size_t)NINNER * NDIM * 2);        // 0.39 MB
  u16* Wkv = (u16*)alloc((size_t)2 * NINNER * NDIM * 2);    // 0.79 MB
  u16* Wo  = (u16*)alloc((size_t)NDIM * NINNER * 2);        // 0.39 MB
  float* fused = (float*)alloc((size_t)NDIM * 20 * 4);      // 30.7 KB BN-folded dw weights
  float* m0 = ktvb + 64 * 4096;
  u16* OutA = yq;   // alias: yq/ykv dead after the pw GEMMs; 25.7 MB fits in their 38.5 MB

  hipMemsetAsync(ktvb, 0, (size_t)64 * 4096 * 4 + 4, stream);

  cvt_kernel<<<1536, 256, 0, stream>>>(wq_pw, wkv_pw, wo, Wq, Wkv, Wo,
                                       wq_dw, wq_g, wq_b, wq_m, wq_v,
                                       wkv_dw, wkv_g, wkv_b, wkv_m, wkv_v, fused);

  dwbn_kernel<<<dim3(49, 12, 8), 256, 0, stream>>>(x, fused, yq, ykv);

  // Q (A=Wq, B=yq -> Qb) + KV swapped (A=ykv, B=Wkv -> KVb) in one launch
  mfma_gemm_qkv<<<dim3(800 + 1600), 256, 0, stream>>>(Wq, yq, Qb, ykv, Wkv, KVb);

  // ktv (448 blocks) + diag (784 blocks) in one launch
  diag_ktv_kernel<<<dim3(448 + 784), 256, 0, stream>>>(Qb, KVb, dgb, m0, ktvb);

  attn_out_kernel<<<dim3(49, 64), 256, 0, stream>>>(Qb, KVb, dgb, ktvb, m0, OutA);

  mfma_gemm<<<dim3(3 * 200), 256, 0, stream>>>(Wo, OutA, NINNER, nullptr, 0, 1, bo, out, 3, 196);
}